// Round 4
// baseline (220.696 us; speedup 1.0000x reference)
//
#include <hip/hip_runtime.h>
#include <hip/hip_bf16.h>

#define BDIM 2
#define SDIM 2048
#define HDIM 16
#define DDIM 64
#define HID  1024
#define MDIM (BDIM * SDIM)  // 4096

typedef __attribute__((ext_vector_type(8))) short short8;
typedef __attribute__((ext_vector_type(4))) short short4v;
typedef __attribute__((ext_vector_type(4))) float f32x4;

__device__ __forceinline__ short f2bf(float f) {
    union { float f; unsigned int i; } x; x.f = f;
    unsigned int r = x.i + 0x7fffu + ((x.i >> 16) & 1u);
    return (short)(r >> 16);
}

// swizzled short-index into a [64 rows][64 shorts] tile; c8 = 16B chunk (0..7)
__device__ __forceinline__ int swz(int row, int c8) {
    return row * 64 + ((c8 ^ (row & 7)) << 3);
}

// ---------------- convert f32 -> bf16 (8 elems/thread) ----------------
__global__ __launch_bounds__(256) void cvt_bf16(const float* __restrict__ in,
                                               short* __restrict__ out, int n) {
    int i = (blockIdx.x * 256 + threadIdx.x) * 8;
    if (i >= n) return;
    float4 a = *(const float4*)(in + i);
    float4 b = *(const float4*)(in + i + 4);
    short8 v;
    v[0] = f2bf(a.x); v[1] = f2bf(a.y); v[2] = f2bf(a.z); v[3] = f2bf(a.w);
    v[4] = f2bf(b.x); v[5] = f2bf(b.y); v[6] = f2bf(b.z); v[7] = f2bf(b.w);
    *(short8*)(out + i) = v;
}

// ------------- transpose 4 f32 weights [K][N] -> bf16 [N][K] -------------
__global__ __launch_bounds__(256) void transpose4(
    const float* __restrict__ w0, const float* __restrict__ w1,
    const float* __restrict__ w2, const float* __restrict__ w3,
    short* __restrict__ o0, short* __restrict__ o1,
    short* __restrict__ o2, short* __restrict__ o3)
{
    const float* src; short* dst;
    int z = blockIdx.z;
    if (z == 0)      { src = w0; dst = o0; }
    else if (z == 1) { src = w1; dst = o1; }
    else if (z == 2) { src = w2; dst = o2; }
    else             { src = w3; dst = o3; }
    __shared__ float t[64][65];
    int r0 = blockIdx.y * 64, c0 = blockIdx.x * 64;
    int rd_r = threadIdx.x >> 4, rd_c = (threadIdx.x & 15) * 4;
    #pragma unroll
    for (int it = 0; it < 4; it++) {
        int rr = rd_r + it * 16;
        float4 v = *(const float4*)(src + (size_t)(r0 + rr) * HID + c0 + rd_c);
        t[rr][rd_c + 0] = v.x; t[rr][rd_c + 1] = v.y;
        t[rr][rd_c + 2] = v.z; t[rr][rd_c + 3] = v.w;
    }
    __syncthreads();
    int or_ = threadIdx.x >> 3, oc8 = (threadIdx.x & 7) * 8;
    #pragma unroll
    for (int half = 0; half < 2; half++) {
        int dr = or_ + half * 32;
        short8 v;
        #pragma unroll
        for (int i = 0; i < 8; i++) v[i] = f2bf(t[oc8 + i][dr]);
        *(short8*)(dst + (size_t)(c0 + dr) * HID + r0 + oc8) = v;
    }
}

// ---------------- GEMM: out = X[M,1024](bf16) @ Wt(bf16,[N][K]) + bias(f32) ----
// mode 0/1: q/k with RoPE -> [B,H,S,D] bf16
// mode 2: v -> V^T [B,H,D,S] bf16 (for attn PV B-fragment)
// mode 3: plain row-major [M,N] f32 (final proj)
__global__ __launch_bounds__(256) void gemm_bf16(
    const short* __restrict__ X,
    const short* __restrict__ Wt0,
    const float* __restrict__ b0, const float* __restrict__ b1, const float* __restrict__ b2,
    const float* __restrict__ cosb, const float* __restrict__ sinb,
    short* __restrict__ out0, float* __restrict__ outf,
    int modeBase)
{
    constexpr int LDK = 40;  // 80B row stride
    __shared__ __align__(16) short Asm[128 * LDK];
    __shared__ __align__(16) short Bsm[128 * LDK];
    int z = blockIdx.z;
    int mode = modeBase + z;
    const short* Wt = Wt0 + (size_t)z * HID * HID;
    const float* bias = (z == 0) ? b0 : (z == 1) ? b1 : b2;
    short* outp = out0 + (size_t)z * MDIM * HID;

    int tid = threadIdx.x;
    int lane = tid & 63, wave = tid >> 6;
    int wr = wave >> 1, wc = wave & 1;
    int m0 = blockIdx.x * 128, n0 = blockIdx.y * 128;
    int sr = tid >> 2, sc = (tid & 3) * 8;
    int lr = lane & 15, lg = lane >> 4;

    f32x4 acc[4][4] = {};

    for (int k0 = 0; k0 < HID; k0 += 32) {
        short8 a0  = *(const short8*)(X  + (size_t)(m0 + sr)      * HID + k0 + sc);
        short8 a1  = *(const short8*)(X  + (size_t)(m0 + sr + 64) * HID + k0 + sc);
        short8 w0v = *(const short8*)(Wt + (size_t)(n0 + sr)      * HID + k0 + sc);
        short8 w1v = *(const short8*)(Wt + (size_t)(n0 + sr + 64) * HID + k0 + sc);
        __syncthreads();
        *(short8*)(Asm + sr * LDK + sc) = a0;
        *(short8*)(Asm + (sr + 64) * LDK + sc) = a1;
        *(short8*)(Bsm + sr * LDK + sc) = w0v;
        *(short8*)(Bsm + (sr + 64) * LDK + sc) = w1v;
        __syncthreads();
        short8 af[4], bfr[4];
        #pragma unroll
        for (int m = 0; m < 4; m++)
            af[m] = *(const short8*)(Asm + (wr * 64 + m * 16 + lr) * LDK + lg * 8);
        #pragma unroll
        for (int n = 0; n < 4; n++)
            bfr[n] = *(const short8*)(Bsm + (wc * 64 + n * 16 + lr) * LDK + lg * 8);
        #pragma unroll
        for (int m = 0; m < 4; m++)
            #pragma unroll
            for (int n = 0; n < 4; n++)
                acc[m][n] = __builtin_amdgcn_mfma_f32_16x16x32_bf16(af[m], bfr[n], acc[m][n], 0, 0, 0);
    }

    #pragma unroll
    for (int m = 0; m < 4; m++) {
        #pragma unroll
        for (int n = 0; n < 4; n++) {
            int gr0 = m0 + wr * 64 + m * 16 + lg * 4;
            int gc  = n0 + wc * 64 + n * 16 + lr;
            if (mode == 3) {
                #pragma unroll
                for (int j = 0; j < 4; j++)
                    outf[(size_t)(gr0 + j) * HID + gc] = acc[m][n][j] + bias[gc];
            } else if (mode == 2) {
                // V^T: [B,H,D,S]; 4 consecutive s per lane -> short4 store
                int bb = gr0 >> 11, s0 = gr0 & (SDIM - 1);
                int h = gc >> 6, dd = gc & 63;
                short4v pk;
                #pragma unroll
                for (int j = 0; j < 4; j++) pk[j] = f2bf(acc[m][n][j] + bias[gc]);
                *(short4v*)(outp + ((size_t)((bb * HDIM + h) * DDIM + dd)) * SDIM + s0) = pk;
            } else {
                #pragma unroll
                for (int j = 0; j < 4; j++) {
                    int gr = gr0 + j;
                    int bb = gr >> 11, s = gr & (SDIM - 1);
                    int h = gc >> 6, dd = gc & 63;
                    float v = acc[m][n][j] + bias[gc];
                    // RoPE: partner (even<->odd col) sits in lane^1
                    float p  = __shfl_xor(v, 1);
                    float cc = cosb[s * 32 + (dd >> 1)];
                    float ss = sinb[s * 32 + (dd >> 1)];
                    v = (dd & 1) ? (p * ss + v * cc) : (v * cc - p * ss);
                    outp[((size_t)((bb * HDIM + h) * SDIM + s)) * DDIM + dd] = f2bf(v);
                }
            }
        }
    }
}

// ---------------- causal flash attention ----------------
// Q,K: [B*H, S, D] bf16.  Vt: [B*H, D, S] bf16.  O: [B, S, H, D] bf16.
// QBLK=128 (2 q-groups of 64 per wave set), KVBLK=64, double-buffered LDS,
// XOR-swizzled tiles, 1 barrier/tile.
__global__ __launch_bounds__(256) void attn_fwd(
    const short* __restrict__ Q,
    const short* __restrict__ K,
    const short* __restrict__ Vt,
    short* __restrict__ O)
{
    __shared__ __align__(16) short Ks[2][64 * 64];
    __shared__ __align__(16) short Vs[2][64 * 64];
    __shared__ __align__(16) short Ps[4][16 * 64];
    int qb = gridDim.x - 1 - blockIdx.x;           // heavy blocks first
    int bh = blockIdx.y;
    int tid = threadIdx.x;
    int lane = tid & 63, wave = tid >> 6;
    int lr = lane & 15, lg = lane >> 4;
    const short* qbase  = Q  + ((size_t)bh * SDIM) * DDIM;
    const short* kbase  = K  + ((size_t)bh * SDIM) * DDIM;
    const short* vtbase = Vt + ((size_t)bh * DDIM) * SDIM;

    // Q fragments: 2 groups of 64 rows, wave owns 16 rows per group
    short8 qf[2][2];
    #pragma unroll
    for (int mi = 0; mi < 2; mi++) {
        int qrow = qb * 128 + mi * 64 + wave * 16 + lr;
        qf[mi][0] = *(const short8*)(qbase + (size_t)qrow * DDIM + lg * 8);
        qf[mi][1] = *(const short8*)(qbase + (size_t)qrow * DDIM + 32 + lg * 8);
    }

    float m_run[2][4], l_run[2][4];
    f32x4 oacc[2][4] = {};
    #pragma unroll
    for (int mi = 0; mi < 2; mi++)
        #pragma unroll
        for (int j = 0; j < 4; j++) { m_run[mi][j] = -1e30f; l_run[mi][j] = 0.f; }

    // staging: K rows (sr_, chunk sc8); Vt rows (vd_, chunks vc8, vc8+1)
    int sr_ = tid >> 3, sc8 = tid & 7;
    int vd_ = tid >> 2, vc8 = (tid & 3) * 2;

    int nt = 2 * qb + 2;
    short8 kreg0, kreg1, vreg0, vreg1;
    {
        kreg0 = *(const short8*)(kbase + (size_t)sr_ * DDIM + sc8 * 8);
        kreg1 = *(const short8*)(kbase + (size_t)(sr_ + 32) * DDIM + sc8 * 8);
        vreg0 = *(const short8*)(vtbase + (size_t)vd_ * SDIM + vc8 * 8);
        vreg1 = *(const short8*)(vtbase + (size_t)vd_ * SDIM + vc8 * 8 + 8);
    }
    // prologue: write tile 0 into buf 0
    *(short8*)(Ks[0] + swz(sr_, sc8))      = kreg0;
    *(short8*)(Ks[0] + swz(sr_ + 32, sc8)) = kreg1;
    *(short8*)(Vs[0] + swz(vd_, vc8))      = vreg0;
    *(short8*)(Vs[0] + swz(vd_, vc8 + 1))  = vreg1;
    if (nt > 1) {
        const short* kg = kbase + (size_t)64 * DDIM;
        kreg0 = *(const short8*)(kg + (size_t)sr_ * DDIM + sc8 * 8);
        kreg1 = *(const short8*)(kg + (size_t)(sr_ + 32) * DDIM + sc8 * 8);
        const short* vg = vtbase + 64;
        vreg0 = *(const short8*)(vg + (size_t)vd_ * SDIM + vc8 * 8);
        vreg1 = *(const short8*)(vg + (size_t)vd_ * SDIM + vc8 * 8 + 8);
    }

    int cur = 0;
    for (int kt = 0; kt < nt; kt++) {
        __syncthreads();   // buf[cur] fully written; buf[cur^1] fully consumed
        if (kt + 1 < nt) {  // write next tile into the other buffer (nobody reads it)
            *(short8*)(Ks[cur ^ 1] + swz(sr_, sc8))      = kreg0;
            *(short8*)(Ks[cur ^ 1] + swz(sr_ + 32, sc8)) = kreg1;
            *(short8*)(Vs[cur ^ 1] + swz(vd_, vc8))      = vreg0;
            *(short8*)(Vs[cur ^ 1] + swz(vd_, vc8 + 1))  = vreg1;
        }
        if (kt + 2 < nt) {  // T14: issue loads for tile kt+2
            const short* kg = kbase + (size_t)((kt + 2) * 64) * DDIM;
            kreg0 = *(const short8*)(kg + (size_t)sr_ * DDIM + sc8 * 8);
            kreg1 = *(const short8*)(kg + (size_t)(sr_ + 32) * DDIM + sc8 * 8);
            const short* vg = vtbase + (kt + 2) * 64;
            vreg0 = *(const short8*)(vg + (size_t)vd_ * SDIM + vc8 * 8);
            vreg1 = *(const short8*)(vg + (size_t)vd_ * SDIM + vc8 * 8 + 8);
        }

        // K fragments (shared by both q-groups)
        short8 kf[2][4];
        #pragma unroll
        for (int ks = 0; ks < 2; ks++)
            #pragma unroll
            for (int n = 0; n < 4; n++)
                kf[ks][n] = *(const short8*)(Ks[cur] + swz(n * 16 + lr, ks * 4 + lg));

        // QK^T for both groups
        f32x4 sf[2][4] = {};
        __builtin_amdgcn_s_setprio(1);
        #pragma unroll
        for (int mi = 0; mi < 2; mi++)
            #pragma unroll
            for (int n = 0; n < 4; n++)
                #pragma unroll
                for (int ks = 0; ks < 2; ks++)
                    sf[mi][n] = __builtin_amdgcn_mfma_f32_16x16x32_bf16(qf[mi][ks], kf[ks][n], sf[mi][n], 0, 0, 0);
        __builtin_amdgcn_s_setprio(0);

        // V fragments (shared by both groups' PV)
        short8 vf[2][4];
        #pragma unroll
        for (int ks = 0; ks < 2; ks++)
            #pragma unroll
            for (int n = 0; n < 4; n++)
                vf[ks][n] = *(const short8*)(Vs[cur] + swz(n * 16 + lr, ks * 4 + lg));

        #pragma unroll
        for (int mi = 0; mi < 2; mi++) {
            if (kt > 2 * qb + mi) continue;          // fully masked for this group
            bool diag = (kt == 2 * qb + mi);
            int qr_g = qb * 128 + mi * 64 + wave * 16 + lg * 4;
            #pragma unroll
            for (int j = 0; j < 4; j++) {
                float sv[4];
                float mx = -1e30f;
                if (diag) {
                    #pragma unroll
                    for (int n = 0; n < 4; n++) {
                        float s = sf[mi][n][j] * 0.125f;
                        int kv_g = kt * 64 + n * 16 + lr;
                        if (kv_g > qr_g + j) s = -1e30f;
                        sv[n] = s;
                        mx = fmaxf(mx, s);
                    }
                } else {
                    #pragma unroll
                    for (int n = 0; n < 4; n++) {
                        float s = sf[mi][n][j] * 0.125f;
                        sv[n] = s;
                        mx = fmaxf(mx, s);
                    }
                }
                #pragma unroll
                for (int off = 1; off < 16; off <<= 1) mx = fmaxf(mx, __shfl_xor(mx, off));
                float mnew = fmaxf(m_run[mi][j], mx);
                float scl = __expf(m_run[mi][j] - mnew);
                float lsum = 0.f;
                #pragma unroll
                for (int n = 0; n < 4; n++) {
                    float p = __expf(sv[n] - mnew);
                    sv[n] = p;
                    lsum += p;
                }
                #pragma unroll
                for (int off = 1; off < 16; off <<= 1) lsum += __shfl_xor(lsum, off);
                l_run[mi][j] = l_run[mi][j] * scl + lsum;
                m_run[mi][j] = mnew;
                int prow = lg * 4 + j;
                #pragma unroll
                for (int n = 0; n < 4; n++) {
                    oacc[mi][n][j] *= scl;
                    int col = n * 16 + lr;
                    Ps[wave][prow * 64 + ((((col >> 3) ^ (prow & 7)) << 3)) + (col & 7)] = f2bf(sv[n]);
                }
            }
            // Ps is per-wave: in-wave DS ordering, no barrier needed
            __builtin_amdgcn_s_setprio(1);
            #pragma unroll
            for (int ks = 0; ks < 2; ks++) {
                short8 pf = *(const short8*)(Ps[wave] + swz(lr, ks * 4 + lg));
                #pragma unroll
                for (int n = 0; n < 4; n++)
                    oacc[mi][n] = __builtin_amdgcn_mfma_f32_16x16x32_bf16(pf, vf[ks][n], oacc[mi][n], 0, 0, 0);
            }
            __builtin_amdgcn_s_setprio(0);
        }
        cur ^= 1;
    }

    int b = bh >> 4, h = bh & 15;
    #pragma unroll
    for (int mi = 0; mi < 2; mi++) {
        #pragma unroll
        for (int n = 0; n < 4; n++) {
            #pragma unroll
            for (int j = 0; j < 4; j++) {
                int s = qb * 128 + mi * 64 + wave * 16 + lg * 4 + j;
                int dd = n * 16 + lr;
                float v = oacc[mi][n][j] / l_run[mi][j];
                O[(((size_t)(b * SDIM + s) * HDIM) + h) * DDIM + dd] = f2bf(v);
            }
        }
    }
}

extern "C" void kernel_launch(void* const* d_in, const int* in_sizes, int n_in,
                              void* d_out, int out_size, void* d_ws, size_t ws_size,
                              hipStream_t stream) {
    const float* x  = (const float*)d_in[0];
    const float* Wq = (const float*)d_in[1];
    const float* bq = (const float*)d_in[2];
    const float* Wk = (const float*)d_in[3];
    const float* bk = (const float*)d_in[4];
    const float* Wv = (const float*)d_in[5];
    const float* bv = (const float*)d_in[6];
    const float* Wo = (const float*)d_in[7];
    const float* bo = (const float*)d_in[8];
    // d_in[9] = mask (causal; computed analytically in-kernel)
    const float* fc = (const float*)d_in[10];
    const float* fs = (const float*)d_in[11];
    float* out = (float*)d_out;
    short* ws  = (short*)d_ws;

    const size_t MM = (size_t)HID * HID;       // 1M elements
    short* xb     = ws;                        // 4*MM  bf16 [M,K]
    short* wt_qkv = ws + 4 * MM;               // 3*MM
    short* wot    = ws + 7 * MM;               // 1*MM
    short* qt     = ws + 8 * MM;               // 4*MM  [B,H,S,D]
    short* ktb    = ws + 12 * MM;              // 4*MM  [B,H,S,D]
    short* vtb    = ws + 16 * MM;              // 4*MM  [B,H,D,S]  (V transposed)
    short* ao     = ws + 20 * MM;              // 4*MM  [B,S,H,D]

    cvt_bf16<<<dim3((MDIM * HID) / (256 * 8)), 256, 0, stream>>>(x, xb, MDIM * HID);
    transpose4<<<dim3(16, 16, 4), 256, 0, stream>>>(Wq, Wk, Wv, Wo,
                                                    wt_qkv, wt_qkv + MM, wt_qkv + 2 * MM, wot);
    gemm_bf16<<<dim3(MDIM / 128, HID / 128, 3), 256, 0, stream>>>(
        xb, wt_qkv, bq, bk, bv, fc, fs, qt, nullptr, 0);
    attn_fwd<<<dim3(SDIM / 128, BDIM * HDIM), 256, 0, stream>>>(qt, ktb, vtb, ao);
    gemm_bf16<<<dim3(MDIM / 128, HID / 128, 1), 256, 0, stream>>>(
        ao, wot, bo, bo, bo, fc, fs, nullptr, out, 3);
}

// Round 5
// 171.186 us; speedup vs baseline: 1.2892x; 1.2892x over previous
//
#include <hip/hip_runtime.h>
#include <hip/hip_bf16.h>

#define BDIM 2
#define SDIM 2048
#define HDIM 16
#define DDIM 64
#define HID  1024
#define MDIM (BDIM * SDIM)  // 4096

typedef __attribute__((ext_vector_type(8))) short short8;
typedef __attribute__((ext_vector_type(4))) short short4v;
typedef __attribute__((ext_vector_type(4))) float f32x4;
typedef __attribute__((ext_vector_type(2))) unsigned int uint2v;

__device__ __forceinline__ short f2bf(float f) {
    union { float f; unsigned int i; } x; x.f = f;
    unsigned int r = x.i + 0x7fffu + ((x.i >> 16) & 1u);
    return (short)(r >> 16);
}

__device__ __forceinline__ unsigned int cvtpk_bf16(float lo, float hi) {
    unsigned int r;
    asm("v_cvt_pk_bf16_f32 %0, %1, %2" : "=v"(r) : "v"(lo), "v"(hi));
    return r;
}

// swizzled short-index into a [64 rows][64 shorts] tile; c8 = 16B chunk (0..7)
__device__ __forceinline__ int swz(int row, int c8) {
    return row * 64 + ((c8 ^ (row & 7)) << 3);
}

// ---------------- convert f32 -> bf16 (8 elems/thread) ----------------
__global__ __launch_bounds__(256) void cvt_bf16(const float* __restrict__ in,
                                               short* __restrict__ out, int n) {
    int i = (blockIdx.x * 256 + threadIdx.x) * 8;
    if (i >= n) return;
    float4 a = *(const float4*)(in + i);
    float4 b = *(const float4*)(in + i + 4);
    short8 v;
    v[0] = f2bf(a.x); v[1] = f2bf(a.y); v[2] = f2bf(a.z); v[3] = f2bf(a.w);
    v[4] = f2bf(b.x); v[5] = f2bf(b.y); v[6] = f2bf(b.z); v[7] = f2bf(b.w);
    *(short8*)(out + i) = v;
}

// ------------- transpose 4 f32 weights [K][N] -> bf16 [N][K] -------------
__global__ __launch_bounds__(256) void transpose4(
    const float* __restrict__ w0, const float* __restrict__ w1,
    const float* __restrict__ w2, const float* __restrict__ w3,
    short* __restrict__ o0, short* __restrict__ o1,
    short* __restrict__ o2, short* __restrict__ o3)
{
    const float* src; short* dst;
    int z = blockIdx.z;
    if (z == 0)      { src = w0; dst = o0; }
    else if (z == 1) { src = w1; dst = o1; }
    else if (z == 2) { src = w2; dst = o2; }
    else             { src = w3; dst = o3; }
    __shared__ float t[64][65];
    int r0 = blockIdx.y * 64, c0 = blockIdx.x * 64;
    int rd_r = threadIdx.x >> 4, rd_c = (threadIdx.x & 15) * 4;
    #pragma unroll
    for (int it = 0; it < 4; it++) {
        int rr = rd_r + it * 16;
        float4 v = *(const float4*)(src + (size_t)(r0 + rr) * HID + c0 + rd_c);
        t[rr][rd_c + 0] = v.x; t[rr][rd_c + 1] = v.y;
        t[rr][rd_c + 2] = v.z; t[rr][rd_c + 3] = v.w;
    }
    __syncthreads();
    int or_ = threadIdx.x >> 3, oc8 = (threadIdx.x & 7) * 8;
    #pragma unroll
    for (int half = 0; half < 2; half++) {
        int dr = or_ + half * 32;
        short8 v;
        #pragma unroll
        for (int i = 0; i < 8; i++) v[i] = f2bf(t[oc8 + i][dr]);
        *(short8*)(dst + (size_t)(c0 + dr) * HID + r0 + oc8) = v;
    }
}

// ---------------- GEMM: out = X[M,1024](bf16) @ Wt(bf16,[N][K]) + bias(f32) ----
__global__ __launch_bounds__(256) void gemm_bf16(
    const short* __restrict__ X,
    const short* __restrict__ Wt0,
    const float* __restrict__ b0, const float* __restrict__ b1, const float* __restrict__ b2,
    const float* __restrict__ cosb, const float* __restrict__ sinb,
    short* __restrict__ out0, float* __restrict__ outf,
    int modeBase)
{
    constexpr int LDK = 40;
    __shared__ __align__(16) short Asm[128 * LDK];
    __shared__ __align__(16) short Bsm[128 * LDK];
    int z = blockIdx.z;
    int mode = modeBase + z;
    const short* Wt = Wt0 + (size_t)z * HID * HID;
    const float* bias = (z == 0) ? b0 : (z == 1) ? b1 : b2;
    short* outp = out0 + (size_t)z * MDIM * HID;

    int tid = threadIdx.x;
    int lane = tid & 63, wave = tid >> 6;
    int wr = wave >> 1, wc = wave & 1;
    int m0 = blockIdx.x * 128, n0 = blockIdx.y * 128;
    int sr = tid >> 2, sc = (tid & 3) * 8;
    int lr = lane & 15, lg = lane >> 4;

    f32x4 acc[4][4] = {};

    for (int k0 = 0; k0 < HID; k0 += 32) {
        short8 a0  = *(const short8*)(X  + (size_t)(m0 + sr)      * HID + k0 + sc);
        short8 a1  = *(const short8*)(X  + (size_t)(m0 + sr + 64) * HID + k0 + sc);
        short8 w0v = *(const short8*)(Wt + (size_t)(n0 + sr)      * HID + k0 + sc);
        short8 w1v = *(const short8*)(Wt + (size_t)(n0 + sr + 64) * HID + k0 + sc);
        __syncthreads();
        *(short8*)(Asm + sr * LDK + sc) = a0;
        *(short8*)(Asm + (sr + 64) * LDK + sc) = a1;
        *(short8*)(Bsm + sr * LDK + sc) = w0v;
        *(short8*)(Bsm + (sr + 64) * LDK + sc) = w1v;
        __syncthreads();
        short8 af[4], bfr[4];
        #pragma unroll
        for (int m = 0; m < 4; m++)
            af[m] = *(const short8*)(Asm + (wr * 64 + m * 16 + lr) * LDK + lg * 8);
        #pragma unroll
        for (int n = 0; n < 4; n++)
            bfr[n] = *(const short8*)(Bsm + (wc * 64 + n * 16 + lr) * LDK + lg * 8);
        #pragma unroll
        for (int m = 0; m < 4; m++)
            #pragma unroll
            for (int n = 0; n < 4; n++)
                acc[m][n] = __builtin_amdgcn_mfma_f32_16x16x32_bf16(af[m], bfr[n], acc[m][n], 0, 0, 0);
    }

    #pragma unroll
    for (int m = 0; m < 4; m++) {
        #pragma unroll
        for (int n = 0; n < 4; n++) {
            int gr0 = m0 + wr * 64 + m * 16 + lg * 4;
            int gc  = n0 + wc * 64 + n * 16 + lr;
            if (mode == 3) {
                #pragma unroll
                for (int j = 0; j < 4; j++)
                    outf[(size_t)(gr0 + j) * HID + gc] = acc[m][n][j] + bias[gc];
            } else if (mode == 2) {
                int bb = gr0 >> 11, s0 = gr0 & (SDIM - 1);
                int h = gc >> 6, dd = gc & 63;
                short4v pk;
                #pragma unroll
                for (int j = 0; j < 4; j++) pk[j] = f2bf(acc[m][n][j] + bias[gc]);
                *(short4v*)(outp + ((size_t)((bb * HDIM + h) * DDIM + dd)) * SDIM + s0) = pk;
            } else {
                #pragma unroll
                for (int j = 0; j < 4; j++) {
                    int gr = gr0 + j;
                    int bb = gr >> 11, s = gr & (SDIM - 1);
                    int h = gc >> 6, dd = gc & 63;
                    float v = acc[m][n][j] + bias[gc];
                    float p  = __shfl_xor(v, 1);
                    float cc = cosb[s * 32 + (dd >> 1)];
                    float ss = sinb[s * 32 + (dd >> 1)];
                    v = (dd & 1) ? (p * ss + v * cc) : (v * cc - p * ss);
                    outp[((size_t)((bb * HDIM + h) * SDIM + s)) * DDIM + dd] = f2bf(v);
                }
            }
        }
    }
}

// ---------------- causal flash attention (swapped-QK softmax) ----------------
// Q,K: [B*H, S, D] bf16.  Vt: [B*H, D, S] bf16.  O: [B, S, H, D] bf16.
// QBLK=64 (wave owns 16 q-rows), KVBLK=64, double-buffered swizzled LDS.
// st = mfma(K,Q): lane (lr,lg) holds P[q=lr][k=n*16+lg*4+j] -> row-local softmax.
__global__ __launch_bounds__(256) void attn_fwd(
    const short* __restrict__ Q,
    const short* __restrict__ K,
    const short* __restrict__ Vt,
    short* __restrict__ O)
{
    __shared__ __align__(16) short Ks[2][64 * 64];
    __shared__ __align__(16) short Vs[2][64 * 64];
    __shared__ __align__(16) short Ps[4][16 * 64];
    int qb = gridDim.x - 1 - blockIdx.x;
    int bh = blockIdx.y;
    int tid = threadIdx.x;
    int lane = tid & 63, wave = tid >> 6;
    int lr = lane & 15, lg = lane >> 4;
    const short* qbase  = Q  + ((size_t)bh * SDIM) * DDIM;
    const short* kbase  = K  + ((size_t)bh * SDIM) * DDIM;
    const short* vtbase = Vt + ((size_t)bh * DDIM) * SDIM;

    const float SCALE = 0.125f * 1.44269504088896340736f;  // 1/sqrt(64) * log2(e)

    int qrow = qb * 64 + wave * 16 + lr;
    short8 qf[2];
    qf[0] = *(const short8*)(qbase + (size_t)qrow * DDIM + lg * 8);
    qf[1] = *(const short8*)(qbase + (size_t)qrow * DDIM + 32 + lg * 8);

    float m_run = -1e30f, l_run = 0.f;
    f32x4 oacc[4] = {};

    int sr_ = tid >> 3, sc8 = tid & 7;
    int vd_ = tid >> 2, vc8 = (tid & 3) * 2;

    int nt = qb + 1;
    short8 kreg0, kreg1, vreg0, vreg1;
    kreg0 = *(const short8*)(kbase + (size_t)sr_ * DDIM + sc8 * 8);
    kreg1 = *(const short8*)(kbase + (size_t)(sr_ + 32) * DDIM + sc8 * 8);
    vreg0 = *(const short8*)(vtbase + (size_t)vd_ * SDIM + vc8 * 8);
    vreg1 = *(const short8*)(vtbase + (size_t)vd_ * SDIM + vc8 * 8 + 8);
    *(short8*)(Ks[0] + swz(sr_, sc8))      = kreg0;
    *(short8*)(Ks[0] + swz(sr_ + 32, sc8)) = kreg1;
    *(short8*)(Vs[0] + swz(vd_, vc8))      = vreg0;
    *(short8*)(Vs[0] + swz(vd_, vc8 + 1))  = vreg1;
    if (nt > 1) {
        const short* kg = kbase + (size_t)64 * DDIM;
        kreg0 = *(const short8*)(kg + (size_t)sr_ * DDIM + sc8 * 8);
        kreg1 = *(const short8*)(kg + (size_t)(sr_ + 32) * DDIM + sc8 * 8);
        const short* vg = vtbase + 64;
        vreg0 = *(const short8*)(vg + (size_t)vd_ * SDIM + vc8 * 8);
        vreg1 = *(const short8*)(vg + (size_t)vd_ * SDIM + vc8 * 8 + 8);
    }

    int bpa = lr * 4;                 // bpermute addr base: lane lr of lg-group 0
    int cur = 0;
    for (int kt = 0; kt < nt; kt++) {
        __syncthreads();
        if (kt + 1 < nt) {
            *(short8*)(Ks[cur ^ 1] + swz(sr_, sc8))      = kreg0;
            *(short8*)(Ks[cur ^ 1] + swz(sr_ + 32, sc8)) = kreg1;
            *(short8*)(Vs[cur ^ 1] + swz(vd_, vc8))      = vreg0;
            *(short8*)(Vs[cur ^ 1] + swz(vd_, vc8 + 1))  = vreg1;
        }
        if (kt + 2 < nt) {
            const short* kg = kbase + (size_t)((kt + 2) * 64) * DDIM;
            kreg0 = *(const short8*)(kg + (size_t)sr_ * DDIM + sc8 * 8);
            kreg1 = *(const short8*)(kg + (size_t)(sr_ + 32) * DDIM + sc8 * 8);
            const short* vg = vtbase + (kt + 2) * 64;
            vreg0 = *(const short8*)(vg + (size_t)vd_ * SDIM + vc8 * 8);
            vreg1 = *(const short8*)(vg + (size_t)vd_ * SDIM + vc8 * 8 + 8);
        }

        // swapped QK^T: st[n][j] = S[q = lr][k = kt*64 + n*16 + lg*4 + j]
        f32x4 st[4] = {};
        __builtin_amdgcn_s_setprio(1);
        #pragma unroll
        for (int ks = 0; ks < 2; ks++) {
            #pragma unroll
            for (int n = 0; n < 4; n++) {
                short8 kf = *(const short8*)(Ks[cur] + swz(n * 16 + lr, ks * 4 + lg));
                st[n] = __builtin_amdgcn_mfma_f32_16x16x32_bf16(kf, qf[ks], st[n], 0, 0, 0);
            }
        }
        __builtin_amdgcn_s_setprio(0);

        // scale + mask (in log2 domain), in-lane row max
        bool diag = (kt == qb);
        float mx = -1e30f;
        if (diag) {
            #pragma unroll
            for (int n = 0; n < 4; n++)
                #pragma unroll
                for (int j = 0; j < 4; j++) {
                    float s = st[n][j] * SCALE;
                    int k = kt * 64 + n * 16 + lg * 4 + j;
                    if (k > qrow) s = -1e30f;
                    st[n][j] = s;
                    mx = fmaxf(mx, s);
                }
        } else {
            #pragma unroll
            for (int n = 0; n < 4; n++)
                #pragma unroll
                for (int j = 0; j < 4; j++) {
                    float s = st[n][j] * SCALE;
                    st[n][j] = s;
                    mx = fmaxf(mx, s);
                }
        }
        mx = fmaxf(mx, __shfl_xor(mx, 16));
        mx = fmaxf(mx, __shfl_xor(mx, 32));
        float mnew = fmaxf(m_run, mx);
        float scl = exp2f(m_run - mnew);
        float lsum = 0.f;
        #pragma unroll
        for (int n = 0; n < 4; n++)
            #pragma unroll
            for (int j = 0; j < 4; j++) {
                float p = exp2f(st[n][j] - mnew);
                st[n][j] = p;
                lsum += p;
            }
        lsum += __shfl_xor(lsum, 16);
        lsum += __shfl_xor(lsum, 32);
        l_run = l_run * scl + lsum;
        m_run = mnew;

        // broadcast scl to oacc row layout (row = lg*4+j lives on lane lg*4+j)
        float rescl[4];
        #pragma unroll
        for (int j = 0; j < 4; j++)
            rescl[j] = __int_as_float(__builtin_amdgcn_ds_bpermute((lg * 4 + j) * 4, __float_as_int(scl)));
        #pragma unroll
        for (int n = 0; n < 4; n++)
            #pragma unroll
            for (int j = 0; j < 4; j++)
                oacc[n][j] *= rescl[j];

        // pack P -> Ps (swizzled), 4x ds_write_b64 per lane
        #pragma unroll
        for (int n = 0; n < 4; n++) {
            uint2v pk;
            pk[0] = cvtpk_bf16(st[n][0], st[n][1]);
            pk[1] = cvtpk_bf16(st[n][2], st[n][3]);
            int addr = lr * 64 + (((n * 2 + (lg >> 1)) ^ (lr & 7)) << 3) + (lg & 1) * 4;
            *(uint2v*)(Ps[wave] + addr) = pk;
        }

        // PV: oacc[n] += P(rows q) * V^T(rows d)
        __builtin_amdgcn_s_setprio(1);
        #pragma unroll
        for (int ks = 0; ks < 2; ks++) {
            short8 pf = *(const short8*)(Ps[wave] + swz(lr, ks * 4 + lg));
            #pragma unroll
            for (int n = 0; n < 4; n++) {
                short8 vf = *(const short8*)(Vs[cur] + swz(n * 16 + lr, ks * 4 + lg));
                oacc[n] = __builtin_amdgcn_mfma_f32_16x16x32_bf16(pf, vf, oacc[n], 0, 0, 0);
            }
        }
        __builtin_amdgcn_s_setprio(0);
        cur ^= 1;
    }

    // epilogue: divide by row sum (broadcast l to oacc layout), write O
    float linv[4];
    #pragma unroll
    for (int j = 0; j < 4; j++)
        linv[j] = 1.f / __int_as_float(__builtin_amdgcn_ds_bpermute((lg * 4 + j) * 4, __float_as_int(l_run)));
    int b = bh >> 4, h = bh & 15;
    #pragma unroll
    for (int n = 0; n < 4; n++) {
        #pragma unroll
        for (int j = 0; j < 4; j++) {
            int s = qb * 64 + wave * 16 + lg * 4 + j;
            int dd = n * 16 + lr;
            float v = oacc[n][j] * linv[j];
            O[(((size_t)(b * SDIM + s) * HDIM) + h) * DDIM + dd] = f2bf(v);
        }
    }
}

extern "C" void kernel_launch(void* const* d_in, const int* in_sizes, int n_in,
                              void* d_out, int out_size, void* d_ws, size_t ws_size,
                              hipStream_t stream) {
    const float* x  = (const float*)d_in[0];
    const float* Wq = (const float*)d_in[1];
    const float* bq = (const float*)d_in[2];
    const float* Wk = (const float*)d_in[3];
    const float* bk = (const float*)d_in[4];
    const float* Wv = (const float*)d_in[5];
    const float* bv = (const float*)d_in[6];
    const float* Wo = (const float*)d_in[7];
    const float* bo = (const float*)d_in[8];
    const float* fc = (const float*)d_in[10];
    const float* fs = (const float*)d_in[11];
    float* out = (float*)d_out;
    short* ws  = (short*)d_ws;

    const size_t MM = (size_t)HID * HID;
    short* xb     = ws;
    short* wt_qkv = ws + 4 * MM;
    short* wot    = ws + 7 * MM;
    short* qt     = ws + 8 * MM;
    short* ktb    = ws + 12 * MM;
    short* vtb    = ws + 16 * MM;   // [B,H,D,S]
    short* ao     = ws + 20 * MM;

    cvt_bf16<<<dim3((MDIM * HID) / (256 * 8)), 256, 0, stream>>>(x, xb, MDIM * HID);
    transpose4<<<dim3(16, 16, 4), 256, 0, stream>>>(Wq, Wk, Wv, Wo,
                                                    wt_qkv, wt_qkv + MM, wt_qkv + 2 * MM, wot);
    gemm_bf16<<<dim3(MDIM / 128, HID / 128, 3), 256, 0, stream>>>(
        xb, wt_qkv, bq, bk, bv, fc, fs, qt, nullptr, 0);
    attn_fwd<<<dim3(SDIM / 64, BDIM * HDIM), 256, 0, stream>>>(qt, ktb, vtb, ao);
    gemm_bf16<<<dim3(MDIM / 128, HID / 128, 1), 256, 0, stream>>>(
        ao, wot, bo, bo, bo, fc, fs, nullptr, out, 3);
}

// Round 6
// 142.141 us; speedup vs baseline: 1.5527x; 1.2043x over previous
//
#include <hip/hip_runtime.h>
#include <hip/hip_bf16.h>

#define BDIM 2
#define SDIM 2048
#define HDIM 16
#define DDIM 64
#define HID  1024
#define MDIM (BDIM * SDIM)  // 4096

typedef __attribute__((ext_vector_type(8))) short short8;
typedef __attribute__((ext_vector_type(4))) short short4v;
typedef __attribute__((ext_vector_type(4))) float f32x4;
typedef __attribute__((ext_vector_type(2))) unsigned int uint2v;

__device__ __forceinline__ float bf2f(short u) {
    union { unsigned int i; float f; } x;
    x.i = ((unsigned int)(unsigned short)u) << 16;
    return x.f;
}
__device__ __forceinline__ short f2bf(float f) {
    union { float f; unsigned int i; } x; x.f = f;
    unsigned int r = x.i + 0x7fffu + ((x.i >> 16) & 1u);
    return (short)(r >> 16);
}
__device__ __forceinline__ unsigned int cvtpk_bf16(float lo, float hi) {
    unsigned int r;
    asm("v_cvt_pk_bf16_f32 %0, %1, %2" : "=v"(r) : "v"(lo), "v"(hi));
    return r;
}
// async global->LDS, 16B per lane; LDS dest must be wave-uniform base
__device__ __forceinline__ void glds16(const short* g, short* l) {
    __builtin_amdgcn_global_load_lds(
        (const __attribute__((address_space(1))) unsigned int*)g,
        (__attribute__((address_space(3))) unsigned int*)l, 16, 0, 0);
}
// swizzled short-index into a [64 rows][64 shorts] tile; c8 = 16B chunk (0..7)
__device__ __forceinline__ int swz(int row, int c8) {
    return row * 64 + ((c8 ^ (row & 7)) << 3);
}

// ---------------- convert f32 -> bf16 (8 elems/thread) ----------------
__global__ __launch_bounds__(256) void cvt_bf16(const float* __restrict__ in,
                                               short* __restrict__ out, int n) {
    int i = (blockIdx.x * 256 + threadIdx.x) * 8;
    if (i >= n) return;
    float4 a = *(const float4*)(in + i);
    float4 b = *(const float4*)(in + i + 4);
    short8 v;
    v[0] = f2bf(a.x); v[1] = f2bf(a.y); v[2] = f2bf(a.z); v[3] = f2bf(a.w);
    v[4] = f2bf(b.x); v[5] = f2bf(b.y); v[6] = f2bf(b.z); v[7] = f2bf(b.w);
    *(short8*)(out + i) = v;
}

// ------------- transpose 4 f32 weights [K][N] -> bf16 [N][K] -------------
__global__ __launch_bounds__(256) void transpose4(
    const float* __restrict__ w0, const float* __restrict__ w1,
    const float* __restrict__ w2, const float* __restrict__ w3,
    short* __restrict__ o0, short* __restrict__ o1,
    short* __restrict__ o2, short* __restrict__ o3)
{
    const float* src; short* dst;
    int z = blockIdx.z;
    if (z == 0)      { src = w0; dst = o0; }
    else if (z == 1) { src = w1; dst = o1; }
    else if (z == 2) { src = w2; dst = o2; }
    else             { src = w3; dst = o3; }
    __shared__ float t[64][65];
    int r0 = blockIdx.y * 64, c0 = blockIdx.x * 64;
    int rd_r = threadIdx.x >> 4, rd_c = (threadIdx.x & 15) * 4;
    #pragma unroll
    for (int it = 0; it < 4; it++) {
        int rr = rd_r + it * 16;
        float4 v = *(const float4*)(src + (size_t)(r0 + rr) * HID + c0 + rd_c);
        t[rr][rd_c + 0] = v.x; t[rr][rd_c + 1] = v.y;
        t[rr][rd_c + 2] = v.z; t[rr][rd_c + 3] = v.w;
    }
    __syncthreads();
    int or_ = threadIdx.x >> 3, oc8 = (threadIdx.x & 7) * 8;
    #pragma unroll
    for (int half = 0; half < 2; half++) {
        int dr = or_ + half * 32;
        short8 v;
        #pragma unroll
        for (int i = 0; i < 8; i++) v[i] = f2bf(t[oc8 + i][dr]);
        *(short8*)(dst + (size_t)(c0 + dr) * HID + r0 + oc8) = v;
    }
}

// ---------------- GEMM (m97-style): out = X[M,1024](bf16) @ Wt + bias ----------
// global_load_lds width-16 staging into linear [128][32] LDS, 2 barriers/K-step.
__global__ __launch_bounds__(256) void gemm_bf16(
    const short* __restrict__ X,
    const short* __restrict__ Wt0,
    const float* __restrict__ b0, const float* __restrict__ b1, const float* __restrict__ b2,
    const float* __restrict__ cosb, const float* __restrict__ sinb,
    short* __restrict__ out0, float* __restrict__ outf,
    int modeBase)
{
    __shared__ __align__(16) short Asm[128 * 32];
    __shared__ __align__(16) short Bsm[128 * 32];
    int z = blockIdx.z;
    int mode = modeBase + z;
    const short* Wt = Wt0 + (size_t)z * HID * HID;
    const float* bias = (z == 0) ? b0 : (z == 1) ? b1 : b2;
    short* outp = out0 + (size_t)z * MDIM * HID;

    int tid = threadIdx.x;
    int lane = tid & 63, wave = tid >> 6;
    int wr = wave >> 1, wc = wave & 1;
    int m0 = blockIdx.x * 128, n0 = blockIdx.y * 128;
    int lr = lane & 15, lg = lane >> 4;
    int lrow = lane >> 2, lcol = (lane & 3) * 8;

    // per-lane global srcs; wave-uniform LDS dests
    const short* ag0 = X  + (size_t)(m0 + wave * 32 + lrow) * HID + lcol;
    const short* ag1 = ag0 + 16 * HID;
    const short* bg0 = Wt + (size_t)(n0 + wave * 32 + lrow) * HID + lcol;
    const short* bg1 = bg0 + 16 * HID;
    short* al0 = Asm + wave * 32 * 32;
    short* al1 = al0 + 16 * 32;
    short* bl0 = Bsm + wave * 32 * 32;
    short* bl1 = bl0 + 16 * 32;

    f32x4 acc[4][4] = {};

    for (int k0 = 0; k0 < HID; k0 += 32) {
        __syncthreads();          // prev tile fully consumed
        glds16(ag0 + k0, al0);
        glds16(ag1 + k0, al1);
        glds16(bg0 + k0, bl0);
        glds16(bg1 + k0, bl1);
        __syncthreads();          // drains vmcnt(0): tile resident
        short8 af[4], bfr[4];
        #pragma unroll
        for (int m = 0; m < 4; m++)
            af[m] = *(const short8*)(Asm + (wr * 64 + m * 16 + lr) * 32 + lg * 8);
        #pragma unroll
        for (int n = 0; n < 4; n++)
            bfr[n] = *(const short8*)(Bsm + (wc * 64 + n * 16 + lr) * 32 + lg * 8);
        __builtin_amdgcn_s_setprio(1);
        #pragma unroll
        for (int m = 0; m < 4; m++)
            #pragma unroll
            for (int n = 0; n < 4; n++)
                acc[m][n] = __builtin_amdgcn_mfma_f32_16x16x32_bf16(af[m], bfr[n], acc[m][n], 0, 0, 0);
        __builtin_amdgcn_s_setprio(0);
    }

    #pragma unroll
    for (int m = 0; m < 4; m++) {
        #pragma unroll
        for (int n = 0; n < 4; n++) {
            int gr0 = m0 + wr * 64 + m * 16 + lg * 4;
            int gc  = n0 + wc * 64 + n * 16 + lr;
            if (mode == 3) {
                #pragma unroll
                for (int j = 0; j < 4; j++)
                    outf[(size_t)(gr0 + j) * HID + gc] = acc[m][n][j] + bias[gc];
            } else if (mode == 2) {
                int bb = gr0 >> 11, s0 = gr0 & (SDIM - 1);
                int h = gc >> 6, dd = gc & 63;
                short4v pk;
                #pragma unroll
                for (int j = 0; j < 4; j++) pk[j] = f2bf(acc[m][n][j] + bias[gc]);
                *(short4v*)(outp + ((size_t)((bb * HDIM + h) * DDIM + dd)) * SDIM + s0) = pk;
            } else {
                #pragma unroll
                for (int j = 0; j < 4; j++) {
                    int gr = gr0 + j;
                    int bb = gr >> 11, s = gr & (SDIM - 1);
                    int h = gc >> 6, dd = gc & 63;
                    float v = acc[m][n][j] + bias[gc];
                    float p  = __shfl_xor(v, 1);
                    float cc = cosb[s * 32 + (dd >> 1)];
                    float ss = sinb[s * 32 + (dd >> 1)];
                    v = (dd & 1) ? (p * ss + v * cc) : (v * cc - p * ss);
                    outp[((size_t)((bb * HDIM + h) * SDIM + s)) * DDIM + dd] = f2bf(v);
                }
            }
        }
    }
}

// ---------------- causal flash attention (paired q-tiles, swapped-QK) --------
// Block bx handles q-tiles qA=bx and qB=31-bx: every block = 33 q-tile-iters.
// Shared K/V staging over kt=0..qB; A active while kt<=qA.
__global__ __launch_bounds__(256) void attn_fwd(
    const short* __restrict__ Q,
    const short* __restrict__ K,
    const short* __restrict__ Vt,
    short* __restrict__ O)
{
    __shared__ __align__(16) short Ks0[64 * 64], Ks1[64 * 64];
    __shared__ __align__(16) short Vs0[64 * 64], Vs1[64 * 64];
    __shared__ __align__(16) short Ps[4][16 * 64];
    int bx = blockIdx.x;                  // 0..15
    int qA = bx, qB = 31 - bx;            // qA < qB
    int bh = blockIdx.y;
    int tid = threadIdx.x;
    int lane = tid & 63, wave = tid >> 6;
    int lr = lane & 15, lg = lane >> 4;
    const short* qbase  = Q  + ((size_t)bh * SDIM) * DDIM;
    const short* kbase  = K  + ((size_t)bh * SDIM) * DDIM;
    const short* vtbase = Vt + ((size_t)bh * DDIM) * SDIM;

    const float SCALE = 0.125f * 1.44269504088896340736f;  // 1/sqrt(64) * log2(e)

    // Q fragments, pre-scaled by SCALE (folds the per-score multiply into Q)
    int rowA = qA * 64 + wave * 16 + lr;
    int rowB = qB * 64 + wave * 16 + lr;
    short8 qfA[2], qfB[2];
    #pragma unroll
    for (int ks = 0; ks < 2; ks++) {
        short8 a = *(const short8*)(qbase + (size_t)rowA * DDIM + ks * 32 + lg * 8);
        short8 b = *(const short8*)(qbase + (size_t)rowB * DDIM + ks * 32 + lg * 8);
        short8 ra, rb;
        #pragma unroll
        for (int i = 0; i < 8; i++) {
            ra[i] = f2bf(bf2f(a[i]) * SCALE);
            rb[i] = f2bf(bf2f(b[i]) * SCALE);
        }
        qfA[ks] = ra; qfB[ks] = rb;
    }

    float mA = -1e30f, lA = 0.f, mB = -1e30f, lB = 0.f;
    f32x4 oaccA[4] = {}, oaccB[4] = {};

    // hoisted LDS offsets
    int sr_ = tid >> 3, sc8 = tid & 7;
    int vd_ = tid >> 2, vc8 = (tid & 3) * 2;
    int kw0 = swz(sr_, sc8), kw1 = swz(sr_ + 32, sc8);
    int vw0 = swz(vd_, vc8), vw1 = swz(vd_, vc8 + 1);
    int fo[8];
    #pragma unroll
    for (int ks = 0; ks < 2; ks++)
        #pragma unroll
        for (int n = 0; n < 4; n++) fo[ks * 4 + n] = swz(n * 16 + lr, ks * 4 + lg);
    int po[2] = { swz(lr, lg), swz(lr, 4 + lg) };
    int pw[4];
    #pragma unroll
    for (int n = 0; n < 4; n++)
        pw[n] = lr * 64 + (((n * 2 + (lg >> 1)) ^ (lr & 7)) << 3) + (lg & 1) * 4;

    int nt = qB + 1;  // >= 17

    // prologue: tile 0 -> buf0; tile 1 -> regs
    short8 kreg0, kreg1, vreg0, vreg1;
    kreg0 = *(const short8*)(kbase + (size_t)sr_ * DDIM + sc8 * 8);
    kreg1 = *(const short8*)(kbase + (size_t)(sr_ + 32) * DDIM + sc8 * 8);
    vreg0 = *(const short8*)(vtbase + (size_t)vd_ * SDIM + vc8 * 8);
    vreg1 = *(const short8*)(vtbase + (size_t)vd_ * SDIM + vc8 * 8 + 8);
    *(short8*)(Ks0 + kw0) = kreg0;
    *(short8*)(Ks0 + kw1) = kreg1;
    *(short8*)(Vs0 + vw0) = vreg0;
    *(short8*)(Vs0 + vw1) = vreg1;
    kreg0 = *(const short8*)(kbase + (size_t)(64 + sr_) * DDIM + sc8 * 8);
    kreg1 = *(const short8*)(kbase + (size_t)(96 + sr_) * DDIM + sc8 * 8);
    vreg0 = *(const short8*)(vtbase + (size_t)vd_ * SDIM + 64 + vc8 * 8);
    vreg1 = *(const short8*)(vtbase + (size_t)vd_ * SDIM + 64 + vc8 * 8 + 8);
    const short* kpre = kbase + (size_t)(128 + sr_) * DDIM + sc8 * 8;
    const short* vpre = vtbase + (size_t)vd_ * SDIM + 128 + vc8 * 8;

    // softmax + PV for one q-tile state
    auto sm_pv = [&](f32x4 (&st)[4], float& m_run, float& l_run, f32x4 (&oacc)[4],
                     int qrow_, bool diag, int kt, short* VsC) {
        if (diag) {
            #pragma unroll
            for (int n = 0; n < 4; n++)
                #pragma unroll
                for (int j = 0; j < 4; j++) {
                    int k = kt * 64 + n * 16 + lg * 4 + j;
                    if (k > qrow_) st[n][j] = -1e30f;
                }
        }
        float m4[4], s4[4];
        #pragma unroll
        for (int n = 0; n < 4; n++)
            m4[n] = fmaxf(fmaxf(st[n][0], st[n][1]), fmaxf(st[n][2], st[n][3]));
        float mx = fmaxf(fmaxf(m4[0], m4[1]), fmaxf(m4[2], m4[3]));
        mx = fmaxf(mx, __shfl_xor(mx, 16));
        mx = fmaxf(mx, __shfl_xor(mx, 32));
        float mnew;
        if (__any(mx > m_run + 8.f)) {       // T13 defer-max: rescale only on real growth
            mnew = fmaxf(m_run, mx);
            float scl = exp2f(m_run - mnew);
            l_run *= scl;
            float rescl[4];
            #pragma unroll
            for (int j = 0; j < 4; j++)
                rescl[j] = __int_as_float(__builtin_amdgcn_ds_bpermute((lg * 4 + j) * 4, __float_as_int(scl)));
            #pragma unroll
            for (int n = 0; n < 4; n++)
                #pragma unroll
                for (int j = 0; j < 4; j++) oacc[n][j] *= rescl[j];
            m_run = mnew;
        } else {
            mnew = m_run;
        }
        #pragma unroll
        for (int n = 0; n < 4; n++) {
            #pragma unroll
            for (int j = 0; j < 4; j++) st[n][j] = exp2f(st[n][j] - mnew);
            s4[n] = (st[n][0] + st[n][1]) + (st[n][2] + st[n][3]);
        }
        float ls = (s4[0] + s4[1]) + (s4[2] + s4[3]);
        ls += __shfl_xor(ls, 16);
        ls += __shfl_xor(ls, 32);
        l_run += ls;
        #pragma unroll
        for (int n = 0; n < 4; n++) {
            uint2v pk;
            pk[0] = cvtpk_bf16(st[n][0], st[n][1]);
            pk[1] = cvtpk_bf16(st[n][2], st[n][3]);
            *(uint2v*)(Ps[wave] + pw[n]) = pk;
        }
        __builtin_amdgcn_s_setprio(1);
        #pragma unroll
        for (int ks = 0; ks < 2; ks++) {
            short8 pf = *(const short8*)(Ps[wave] + po[ks]);
            #pragma unroll
            for (int n = 0; n < 4; n++) {
                short8 vf = *(const short8*)(VsC + fo[ks * 4 + n]);
                oacc[n] = __builtin_amdgcn_mfma_f32_16x16x32_bf16(pf, vf, oacc[n], 0, 0, 0);
            }
        }
        __builtin_amdgcn_s_setprio(0);
    };

    auto tile = [&](int kt, short* KsC, short* VsC, short* KsN, short* VsN) {
        __syncthreads();                       // buf C ready; buf N free
        if (kt + 1 < nt) {
            *(short8*)(KsN + kw0) = kreg0;
            *(short8*)(KsN + kw1) = kreg1;
            *(short8*)(VsN + vw0) = vreg0;
            *(short8*)(VsN + vw1) = vreg1;
        }
        if (kt + 2 < nt) {                     // T14 prefetch
            kreg0 = *(const short8*)(kpre);
            kreg1 = *(const short8*)(kpre + 32 * DDIM);
            vreg0 = *(const short8*)(vpre);
            vreg1 = *(const short8*)(vpre + 8);
        }
        kpre += 64 * DDIM;
        vpre += 64;

        bool actA = (kt <= qA);
        f32x4 stA[4] = {}, stB[4] = {};
        __builtin_amdgcn_s_setprio(1);
        #pragma unroll
        for (int ks = 0; ks < 2; ks++) {
            short8 kf[4];
            #pragma unroll
            for (int n = 0; n < 4; n++) kf[n] = *(const short8*)(KsC + fo[ks * 4 + n]);
            #pragma unroll
            for (int n = 0; n < 4; n++)
                stB[n] = __builtin_amdgcn_mfma_f32_16x16x32_bf16(kf[n], qfB[ks], stB[n], 0, 0, 0);
            if (actA)
                #pragma unroll
                for (int n = 0; n < 4; n++)
                    stA[n] = __builtin_amdgcn_mfma_f32_16x16x32_bf16(kf[n], qfA[ks], stA[n], 0, 0, 0);
        }
        __builtin_amdgcn_s_setprio(0);
        if (actA) sm_pv(stA, mA, lA, oaccA, rowA, kt == qA, kt, VsC);
        sm_pv(stB, mB, lB, oaccB, rowB, kt == qB, kt, VsC);
    };

    for (int kt = 0; kt < nt; kt += 2) {
        tile(kt, Ks0, Vs0, Ks1, Vs1);
        if (kt + 1 < nt) tile(kt + 1, Ks1, Vs1, Ks0, Vs0);
    }

    int b = bh >> 4, h = bh & 15;
    auto epi = [&](f32x4 (&oacc)[4], float l_run, int qb_) {
        float linv[4];
        #pragma unroll
        for (int j = 0; j < 4; j++)
            linv[j] = 1.f / __int_as_float(__builtin_amdgcn_ds_bpermute((lg * 4 + j) * 4, __float_as_int(l_run)));
        #pragma unroll
        for (int n = 0; n < 4; n++)
            #pragma unroll
            for (int j = 0; j < 4; j++) {
                int s = qb_ * 64 + wave * 16 + lg * 4 + j;
                int dd = n * 16 + lr;
                O[(((size_t)(b * SDIM + s) * HDIM) + h) * DDIM + dd] = f2bf(oacc[n][j] * linv[j]);
            }
    };
    epi(oaccA, lA, qA);
    epi(oaccB, lB, qB);
}

extern "C" void kernel_launch(void* const* d_in, const int* in_sizes, int n_in,
                              void* d_out, int out_size, void* d_ws, size_t ws_size,
                              hipStream_t stream) {
    const float* x  = (const float*)d_in[0];
    const float* Wq = (const float*)d_in[1];
    const float* bq = (const float*)d_in[2];
    const float* Wk = (const float*)d_in[3];
    const float* bk = (const float*)d_in[4];
    const float* Wv = (const float*)d_in[5];
    const float* bv = (const float*)d_in[6];
    const float* Wo = (const float*)d_in[7];
    const float* bo = (const float*)d_in[8];
    const float* fc = (const float*)d_in[10];
    const float* fs = (const float*)d_in[11];
    float* out = (float*)d_out;
    short* ws  = (short*)d_ws;

    const size_t MM = (size_t)HID * HID;
    short* xb     = ws;
    short* wt_qkv = ws + 4 * MM;
    short* wot    = ws + 7 * MM;
    short* qt     = ws + 8 * MM;
    short* ktb    = ws + 12 * MM;
    short* vtb    = ws + 16 * MM;   // [B,H,D,S]
    short* ao     = ws + 20 * MM;

    cvt_bf16<<<dim3((MDIM * HID) / (256 * 8)), 256, 0, stream>>>(x, xb, MDIM * HID);
    transpose4<<<dim3(16, 16, 4), 256, 0, stream>>>(Wq, Wk, Wv, Wo,
                                                    wt_qkv, wt_qkv + MM, wt_qkv + 2 * MM, wot);
    gemm_bf16<<<dim3(MDIM / 128, HID / 128, 3), 256, 0, stream>>>(
        xb, wt_qkv, bq, bk, bv, fc, fs, qt, nullptr, 0);
    attn_fwd<<<dim3(16, BDIM * HDIM), 256, 0, stream>>>(qt, ktb, vtb, ao);
    gemm_bf16<<<dim3(MDIM / 128, HID / 128, 1), 256, 0, stream>>>(
        ao, wot, bo, bo, bo, fc, fs, nullptr, out, 3);
}